// Round 1
// baseline (364.584 us; speedup 1.0000x reference)
//
#include <hip/hip_runtime.h>

// ---------- types ----------
typedef __bf16 bf16x8 __attribute__((ext_vector_type(8)));
typedef float  f32x4  __attribute__((ext_vector_type(4)));
typedef unsigned short us8 __attribute__((ext_vector_type(8)));

__device__ __forceinline__ unsigned short f2bf(float f) {
  unsigned int u = __builtin_bit_cast(unsigned int, f);
  u += 0x7FFFu + ((u >> 16) & 1u);   // round-to-nearest-even
  return (unsigned short)(u >> 16);
}
__device__ __forceinline__ float bf2f(unsigned short h) {
  unsigned int u = ((unsigned int)h) << 16;
  return __builtin_bit_cast(float, u);
}

// ---------- f32 -> bf16 cast, 8 elems/thread ----------
__global__ void cast_f32_bf16(const float* __restrict__ in,
                              unsigned short* __restrict__ out, long n) {
  long i = ((long)blockIdx.x * blockDim.x + threadIdx.x) * 8;
  if (i >= n) return;
  f32x4 a = *(const f32x4*)(in + i);
  f32x4 b = *(const f32x4*)(in + i + 4);
  us8 o;
  o[0] = f2bf(a[0]); o[1] = f2bf(a[1]); o[2] = f2bf(a[2]); o[3] = f2bf(a[3]);
  o[4] = f2bf(b[0]); o[5] = f2bf(b[1]); o[6] = f2bf(b[2]); o[7] = f2bf(b[3]);
  *(us8*)(out + i) = o;
}

// ---------- GEMM: C[M,N] = A[M,K] * Bm[N,K]^T (+bias), m97 structure ----------
// EPI=0: bf16 output (C = bf16(acc + bias))
// EPI=1: f32 output with tanh (C = tanhf(acc + bias))
template<int EPI>
__global__ __launch_bounds__(256) void gemm_bt(
    const unsigned short* __restrict__ A,
    const unsigned short* __restrict__ Bm,
    void* __restrict__ Cout,
    const float* __restrict__ bias,
    int M, int N, int K)
{
  __shared__ unsigned short lsA[2][128 * 32];
  __shared__ unsigned short lsB[2][128 * 32];

  const int tid  = threadIdx.x;
  const int lane = tid & 63;
  const int wave = tid >> 6;
  const int wr = wave >> 1, wc = wave & 1;
  const int m0 = blockIdx.y * 128;
  const int n0 = blockIdx.x * 128;

  auto stage = [&](int buf, int kt) {
    const int k0 = kt * 32;
#pragma unroll
    for (int it = 0; it < 2; ++it) {
      int li  = it * 256 + tid;          // 0..511
      int row = li >> 2;                 // 0..127
      int col = (li & 3) << 3;           // 0,8,16,24
      const unsigned short* ga = A  + (size_t)(m0 + row) * K + k0 + col;
      const unsigned short* gb = Bm + (size_t)(n0 + row) * K + k0 + col;
      __builtin_amdgcn_global_load_lds(
          (const __attribute__((address_space(1))) unsigned int*)ga,
          (__attribute__((address_space(3))) unsigned int*)&lsA[buf][li * 8],
          16, 0, 0);
      __builtin_amdgcn_global_load_lds(
          (const __attribute__((address_space(1))) unsigned int*)gb,
          (__attribute__((address_space(3))) unsigned int*)&lsB[buf][li * 8],
          16, 0, 0);
    }
  };

  f32x4 acc[4][4];
#pragma unroll
  for (int i = 0; i < 4; ++i)
#pragma unroll
    for (int j = 0; j < 4; ++j) acc[i][j] = f32x4{0.f, 0.f, 0.f, 0.f};

  const int nk = K >> 5;
  stage(0, 0);
  __syncthreads();
  int buf = 0;
  for (int kt = 0; kt < nk; ++kt) {
    if (kt + 1 < nk) stage(buf ^ 1, kt + 1);
    const int kofs = (lane >> 4) << 3;       // 0,8,16,24
    const int rA = wr * 64 + (lane & 15);
    const int rB = wc * 64 + (lane & 15);
    bf16x8 af[4], bfr[4];
#pragma unroll
    for (int m = 0; m < 4; ++m)
      af[m] = *(const bf16x8*)&lsA[buf][(rA + m * 16) * 32 + kofs];
#pragma unroll
    for (int n = 0; n < 4; ++n)
      bfr[n] = *(const bf16x8*)&lsB[buf][(rB + n * 16) * 32 + kofs];
#pragma unroll
    for (int m = 0; m < 4; ++m)
#pragma unroll
      for (int n = 0; n < 4; ++n)
        acc[m][n] = __builtin_amdgcn_mfma_f32_16x16x32_bf16(af[m], bfr[n], acc[m][n], 0, 0, 0);
    __syncthreads();
    buf ^= 1;
  }

  // epilogue: C/D layout col = lane&15, row = (lane>>4)*4 + r  [m89/m91 verified]
  const int colb = n0 + wc * 64 + (lane & 15);
  const int rowb = m0 + wr * 64 + ((lane >> 4) << 2);
#pragma unroll
  for (int n = 0; n < 4; ++n) {
    int col = colb + n * 16;
    float bv = bias ? bias[col] : 0.f;
#pragma unroll
    for (int m = 0; m < 4; ++m) {
      int row = rowb + m * 16;
#pragma unroll
      for (int r = 0; r < 4; ++r) {
        float v = acc[m][n][r] + bv;
        if (EPI == 0) {
          ((unsigned short*)Cout)[(size_t)(row + r) * N + col] = f2bf(v);
        } else {
          ((float*)Cout)[(size_t)(row + r) * N + col] = tanhf(v);
        }
      }
    }
  }
}

// ---------- GRU gate fusion ----------
// gi, gh: [B, 3H] bf16 (biases already added in GEMM epilogues)
// h: [B, H] f32. Writes h_new f32 (into d_out tail) and h_new bf16 (ws).
__global__ void gru_gate(const unsigned short* __restrict__ gi,
                         const unsigned short* __restrict__ gh,
                         const float* __restrict__ h,
                         float* __restrict__ hnew_f32,
                         unsigned short* __restrict__ hnew_b) {
  long idx = (long)blockIdx.x * blockDim.x + threadIdx.x;
  long e = idx * 8;                      // element index into [B*H]
  long b = e >> 10;
  int  j = (int)(e & 1023);
  const unsigned short* gib = gi + b * 3072 + j;
  const unsigned short* ghb = gh + b * 3072 + j;
  us8 ir = *(const us8*)(gib);
  us8 iz = *(const us8*)(gib + 1024);
  us8 in_ = *(const us8*)(gib + 2048);
  us8 hr = *(const us8*)(ghb);
  us8 hz = *(const us8*)(ghb + 1024);
  us8 hn = *(const us8*)(ghb + 2048);
  f32x4 h0 = *(const f32x4*)(h + b * 1024 + j);
  f32x4 h1 = *(const f32x4*)(h + b * 1024 + j + 4);
  f32x4 o0, o1;
  us8 ob;
#pragma unroll
  for (int t = 0; t < 8; ++t) {
    float r = 1.f / (1.f + __expf(-(bf2f(ir[t]) + bf2f(hr[t]))));
    float z = 1.f / (1.f + __expf(-(bf2f(iz[t]) + bf2f(hz[t]))));
    float nn = tanhf(bf2f(in_[t]) + r * bf2f(hn[t]));
    float hv = (t < 4) ? h0[t] : h1[t - 4];
    float o = (1.f - z) * nn + z * hv;
    if (t < 4) o0[t] = o; else o1[t - 4] = o;
    ob[t] = f2bf(o);
  }
  *(f32x4*)(hnew_f32 + e) = o0;
  *(f32x4*)(hnew_f32 + e + 4) = o1;
  *(us8*)(hnew_b + e) = ob;
}

// ---------- launch ----------
extern "C" void kernel_launch(void* const* d_in, const int* in_sizes, int n_in,
                              void* d_out, int out_size, void* d_ws, size_t ws_size,
                              hipStream_t stream) {
  const int B = 16384, H = 1024, O = 512;
  const float* inp    = (const float*)d_in[0];
  const float* hidden = (const float*)d_in[1];
  const float* w_ih   = (const float*)d_in[2];
  const float* w_hh   = (const float*)d_in[3];
  const float* b_ih   = (const float*)d_in[4];
  const float* b_hh   = (const float*)d_in[5];
  const float* w_out  = (const float*)d_in[6];
  const float* b_out  = (const float*)d_in[7];

  float* out      = (float*)d_out;                     // [B, O] f32
  float* hnew_out = out + (size_t)B * O;               // [1, B, H] f32

  // workspace carve-up (all bf16 buffers)
  char* ws = (char*)d_ws;
  size_t need = 0;
  auto carve = [&](size_t elems) {
    unsigned short* p = (unsigned short*)(ws + need);
    need += elems * 2;
    return p;
  };
  unsigned short* inp_b  = carve((size_t)B * O);       // 16 MB
  unsigned short* h_b    = carve((size_t)B * H);       // 32 MB
  unsigned short* wih_b  = carve((size_t)3 * H * O);   // 3 MB
  unsigned short* whh_b  = carve((size_t)3 * H * H);   // 6 MB
  unsigned short* wout_b = carve((size_t)O * H);       // 1 MB
  unsigned short* gi     = carve((size_t)B * 3 * H);   // 96 MB
  unsigned short* gh     = carve((size_t)B * 3 * H);   // 96 MB
  unsigned short* hnew_b = carve((size_t)B * H);       // 32 MB
  if (ws_size < need) return;  // insufficient scratch -> clean correctness fail

  // casts
  auto cast = [&](const float* src, unsigned short* dst, long n) {
    cast_f32_bf16<<<dim3((unsigned)((n / 8 + 255) / 256)), dim3(256), 0, stream>>>(src, dst, n);
  };
  cast(inp,    inp_b,  (long)B * O);
  cast(hidden, h_b,    (long)B * H);
  cast(w_ih,   wih_b,  (long)3 * H * O);
  cast(w_hh,   whh_b,  (long)3 * H * H);
  cast(w_out,  wout_b, (long)O * H);

  // gi = inp @ w_ih^T + b_ih   (bf16 out)
  gemm_bt<0><<<dim3(3 * H / 128, B / 128), dim3(256), 0, stream>>>(
      inp_b, wih_b, (void*)gi, b_ih, B, 3 * H, O);
  // gh = h @ w_hh^T + b_hh     (bf16 out)
  gemm_bt<0><<<dim3(3 * H / 128, B / 128), dim3(256), 0, stream>>>(
      h_b, whh_b, (void*)gh, b_hh, B, 3 * H, H);

  // gates -> h_new (f32 into d_out tail, bf16 into ws)
  gru_gate<<<dim3((unsigned)((size_t)B * H / 8 / 256)), dim3(256), 0, stream>>>(
      gi, gh, hidden, hnew_out, hnew_b);

  // out = tanh(h_new @ w_out^T + b_out)  (f32 out)
  gemm_bt<1><<<dim3(O / 128, B / 128), dim3(256), 0, stream>>>(
      hnew_b, wout_b, d_out, b_out, B, O, H);
}

// Round 2
// 284.982 us; speedup vs baseline: 1.2793x; 1.2793x over previous
//
#include <hip/hip_runtime.h>

// ---------- types ----------
typedef __bf16 bf16x8 __attribute__((ext_vector_type(8)));
typedef float  f32x4  __attribute__((ext_vector_type(4)));
typedef unsigned short us8 __attribute__((ext_vector_type(8)));

__device__ __forceinline__ unsigned short f2bf(float f) {
  unsigned int u = __builtin_bit_cast(unsigned int, f);
  u += 0x7FFFu + ((u >> 16) & 1u);   // round-to-nearest-even
  return (unsigned short)(u >> 16);
}
__device__ __forceinline__ float bf2f(unsigned short h) {
  unsigned int u = ((unsigned int)h) << 16;
  return __builtin_bit_cast(float, u);
}
__device__ __forceinline__ float sigmoid_f(float x) {
  return 1.f / (1.f + __expf(-x));
}
// NaN-safe fast tanh: 1 - 2/(e^{2x}+1); exp->inf gives 1, exp->0 gives -1.
__device__ __forceinline__ float tanh_f(float x) {
  float e = __expf(2.f * x);
  return 1.f - 2.f / (e + 1.f);
}

// ---------- f32 -> bf16 cast, 8 elems/thread ----------
__global__ void cast_f32_bf16(const float* __restrict__ in,
                              unsigned short* __restrict__ out, long n) {
  long i = ((long)blockIdx.x * blockDim.x + threadIdx.x) * 8;
  if (i >= n) return;
  f32x4 a = *(const f32x4*)(in + i);
  f32x4 b = *(const f32x4*)(in + i + 4);
  us8 o;
  o[0] = f2bf(a[0]); o[1] = f2bf(a[1]); o[2] = f2bf(a[2]); o[3] = f2bf(a[3]);
  o[4] = f2bf(b[0]); o[5] = f2bf(b[1]); o[6] = f2bf(b[2]); o[7] = f2bf(b[3]);
  *(us8*)(out + i) = o;
}

// ---------- Fused GRU cell: both GEMMs + gate math ----------
// Block tile: 128 rows (batch) x 64 cols (H). 4 waves (2 row x 2 col),
// wave tile 64x32 per gate-accumulator. Four acc sets: r, z, i_n, h_n.
// Phase 0: A=inp_b [B,512],  W=wih [3*1024,512],  accR/accZ/accNi
// Phase 1: A=h_b   [B,1024], W=whh [3*1024,1024], accR/accZ/accNh
__global__ __launch_bounds__(256, 2) void fused_gru(
    const unsigned short* __restrict__ inp_b,
    const unsigned short* __restrict__ h_b,
    const unsigned short* __restrict__ wih,
    const unsigned short* __restrict__ whh,
    const float* __restrict__ b_ih,
    const float* __restrict__ b_hh,
    const float* __restrict__ hidden,      // [B,1024] f32
    float* __restrict__ hnew_f32,
    unsigned short* __restrict__ hnew_b)
{
  __shared__ unsigned short lsA[2][128 * 32];      // 2 x 8KB
  __shared__ unsigned short lsB[2][3][64 * 32];    // 2 x 3 x 4KB

  const int tid  = threadIdx.x;
  const int lane = tid & 63;
  const int wave = tid >> 6;
  const int wr = wave >> 1, wc = wave & 1;
  const int m0 = blockIdx.y * 128;   // batch rows
  const int n0 = blockIdx.x * 64;    // H cols

  auto stage = [&](int buf, const unsigned short* Abase, const unsigned short* Wbase,
                   int KA, int kt) {
    const int k0 = kt * 32;
    // A tile: 128x32 = 8KB = 512 x 16B
#pragma unroll
    for (int it = 0; it < 2; ++it) {
      int li  = it * 256 + tid;
      int row = li >> 2;
      int col = (li & 3) << 3;
      const unsigned short* ga = Abase + (size_t)(m0 + row) * KA + k0 + col;
      __builtin_amdgcn_global_load_lds(
          (const __attribute__((address_space(1))) unsigned int*)ga,
          (__attribute__((address_space(3))) unsigned int*)&lsA[buf][li * 8],
          16, 0, 0);
    }
    // B tiles: per gate 64x32 = 4KB = 256 x 16B
#pragma unroll
    for (int g = 0; g < 3; ++g) {
      int row = tid >> 2;
      int col = (tid & 3) << 3;
      const unsigned short* gb = Wbase + (size_t)(g * 1024 + n0 + row) * KA + k0 + col;
      __builtin_amdgcn_global_load_lds(
          (const __attribute__((address_space(1))) unsigned int*)gb,
          (__attribute__((address_space(3))) unsigned int*)&lsB[buf][g][tid * 8],
          16, 0, 0);
    }
  };

  f32x4 accR[4][2], accZ[4][2], accNi[4][2], accNh[4][2];
#pragma unroll
  for (int m = 0; m < 4; ++m)
#pragma unroll
    for (int n = 0; n < 2; ++n) {
      accR[m][n]  = f32x4{0.f, 0.f, 0.f, 0.f};
      accZ[m][n]  = f32x4{0.f, 0.f, 0.f, 0.f};
      accNi[m][n] = f32x4{0.f, 0.f, 0.f, 0.f};
      accNh[m][n] = f32x4{0.f, 0.f, 0.f, 0.f};
    }

  const int kofs = (lane >> 4) << 3;
  const int rA = wr * 64 + (lane & 15);
  const int rB = wc * 32 + (lane & 15);

  // compute one K-step from buf; PH selects which N-acc receives gate 2
  auto compute = [&](int buf, f32x4 (*accN)[2]) {
    bf16x8 af[4], bfr[3][2];
#pragma unroll
    for (int m = 0; m < 4; ++m)
      af[m] = *(const bf16x8*)&lsA[buf][(rA + m * 16) * 32 + kofs];
#pragma unroll
    for (int g = 0; g < 3; ++g)
#pragma unroll
      for (int n = 0; n < 2; ++n)
        bfr[g][n] = *(const bf16x8*)&lsB[buf][g][(rB + n * 16) * 32 + kofs];
#pragma unroll
    for (int m = 0; m < 4; ++m)
#pragma unroll
      for (int n = 0; n < 2; ++n) {
        accR[m][n] = __builtin_amdgcn_mfma_f32_16x16x32_bf16(af[m], bfr[0][n], accR[m][n], 0, 0, 0);
        accZ[m][n] = __builtin_amdgcn_mfma_f32_16x16x32_bf16(af[m], bfr[1][n], accZ[m][n], 0, 0, 0);
        accN[m][n] = __builtin_amdgcn_mfma_f32_16x16x32_bf16(af[m], bfr[2][n], accN[m][n], 0, 0, 0);
      }
  };

  const int nk0 = 512 >> 5;    // 16
  const int nk1 = 1024 >> 5;   // 32

  int buf = 0;
  stage(0, inp_b, wih, 512, 0);
  __syncthreads();
  for (int kt = 0; kt < nk0; ++kt) {
    if (kt + 1 < nk0) stage(buf ^ 1, inp_b, wih, 512, kt + 1);
    else              stage(buf ^ 1, h_b,   whh, 1024, 0);
    compute(buf, accNi);
    __syncthreads();
    buf ^= 1;
  }
  for (int kt = 0; kt < nk1; ++kt) {
    if (kt + 1 < nk1) stage(buf ^ 1, h_b, whh, 1024, kt + 1);
    compute(buf, accNh);
    __syncthreads();
    buf ^= 1;
  }

  // ---- epilogue: gate math + blend ----
  // C/D layout: col = lane&15, row = (lane>>4)*4 + r
  const int colb = n0 + wc * 32 + (lane & 15);
  const int rowb = m0 + wr * 64 + ((lane >> 4) << 2);
#pragma unroll
  for (int n = 0; n < 2; ++n) {
    int c = colb + n * 16;
    float br = b_ih[c]        + b_hh[c];
    float bz = b_ih[1024 + c] + b_hh[1024 + c];
    float bni = b_ih[2048 + c];
    float bnh = b_hh[2048 + c];
#pragma unroll
    for (int m = 0; m < 4; ++m) {
      int row = rowb + m * 16;
#pragma unroll
      for (int r = 0; r < 4; ++r) {
        float rg = sigmoid_f(accR[m][n][r] + br);
        float zg = sigmoid_f(accZ[m][n][r] + bz);
        float ng = tanh_f((accNi[m][n][r] + bni) + rg * (accNh[m][n][r] + bnh));
        float ho = hidden[(size_t)(row + r) * 1024 + c];
        float hv = (1.f - zg) * ng + zg * ho;
        hnew_f32[(size_t)(row + r) * 1024 + c] = hv;
        hnew_b [(size_t)(row + r) * 1024 + c] = f2bf(hv);
      }
    }
  }
}

// ---------- out GEMM: C[M,N] = tanh(A[M,K] * Bm[N,K]^T + bias), f32 out ----------
__global__ __launch_bounds__(256) void gemm_out(
    const unsigned short* __restrict__ A,
    const unsigned short* __restrict__ Bm,
    float* __restrict__ Cout,
    const float* __restrict__ bias,
    int M, int N, int K)
{
  __shared__ unsigned short lsA[2][128 * 32];
  __shared__ unsigned short lsB[2][128 * 32];

  const int tid  = threadIdx.x;
  const int lane = tid & 63;
  const int wave = tid >> 6;
  const int wr = wave >> 1, wc = wave & 1;
  const int m0 = blockIdx.y * 128;
  const int n0 = blockIdx.x * 128;

  auto stage = [&](int buf, int kt) {
    const int k0 = kt * 32;
#pragma unroll
    for (int it = 0; it < 2; ++it) {
      int li  = it * 256 + tid;
      int row = li >> 2;
      int col = (li & 3) << 3;
      const unsigned short* ga = A  + (size_t)(m0 + row) * K + k0 + col;
      const unsigned short* gb = Bm + (size_t)(n0 + row) * K + k0 + col;
      __builtin_amdgcn_global_load_lds(
          (const __attribute__((address_space(1))) unsigned int*)ga,
          (__attribute__((address_space(3))) unsigned int*)&lsA[buf][li * 8],
          16, 0, 0);
      __builtin_amdgcn_global_load_lds(
          (const __attribute__((address_space(1))) unsigned int*)gb,
          (__attribute__((address_space(3))) unsigned int*)&lsB[buf][li * 8],
          16, 0, 0);
    }
  };

  f32x4 acc[4][4];
#pragma unroll
  for (int i = 0; i < 4; ++i)
#pragma unroll
    for (int j = 0; j < 4; ++j) acc[i][j] = f32x4{0.f, 0.f, 0.f, 0.f};

  const int nk = K >> 5;
  stage(0, 0);
  __syncthreads();
  int buf = 0;
  for (int kt = 0; kt < nk; ++kt) {
    if (kt + 1 < nk) stage(buf ^ 1, kt + 1);
    const int kofs = (lane >> 4) << 3;
    const int rA = wr * 64 + (lane & 15);
    const int rB = wc * 64 + (lane & 15);
    bf16x8 af[4], bfr[4];
#pragma unroll
    for (int m = 0; m < 4; ++m)
      af[m] = *(const bf16x8*)&lsA[buf][(rA + m * 16) * 32 + kofs];
#pragma unroll
    for (int n = 0; n < 4; ++n)
      bfr[n] = *(const bf16x8*)&lsB[buf][(rB + n * 16) * 32 + kofs];
#pragma unroll
    for (int m = 0; m < 4; ++m)
#pragma unroll
      for (int n = 0; n < 4; ++n)
        acc[m][n] = __builtin_amdgcn_mfma_f32_16x16x32_bf16(af[m], bfr[n], acc[m][n], 0, 0, 0);
    __syncthreads();
    buf ^= 1;
  }

  const int colb = n0 + wc * 64 + (lane & 15);
  const int rowb = m0 + wr * 64 + ((lane >> 4) << 2);
#pragma unroll
  for (int n = 0; n < 4; ++n) {
    int col = colb + n * 16;
    float bv = bias[col];
#pragma unroll
    for (int m = 0; m < 4; ++m) {
      int row = rowb + m * 16;
#pragma unroll
      for (int r = 0; r < 4; ++r) {
        Cout[(size_t)(row + r) * N + col] = tanh_f(acc[m][n][r] + bv);
      }
    }
  }
}

// ---------- launch ----------
extern "C" void kernel_launch(void* const* d_in, const int* in_sizes, int n_in,
                              void* d_out, int out_size, void* d_ws, size_t ws_size,
                              hipStream_t stream) {
  const int B = 16384, H = 1024, O = 512;
  const float* inp    = (const float*)d_in[0];
  const float* hidden = (const float*)d_in[1];
  const float* w_ih   = (const float*)d_in[2];
  const float* w_hh   = (const float*)d_in[3];
  const float* b_ih   = (const float*)d_in[4];
  const float* b_hh   = (const float*)d_in[5];
  const float* w_out  = (const float*)d_in[6];
  const float* b_out  = (const float*)d_in[7];

  float* out      = (float*)d_out;                     // [B, O] f32
  float* hnew_out = out + (size_t)B * O;               // [1, B, H] f32

  char* ws = (char*)d_ws;
  size_t need = 0;
  auto carve = [&](size_t elems) {
    unsigned short* p = (unsigned short*)(ws + need);
    need += elems * 2;
    return p;
  };
  unsigned short* inp_b  = carve((size_t)B * O);       // 16 MB
  unsigned short* h_b    = carve((size_t)B * H);       // 32 MB
  unsigned short* wih_b  = carve((size_t)3 * H * O);   // 3 MB
  unsigned short* whh_b  = carve((size_t)3 * H * H);   // 6 MB
  unsigned short* wout_b = carve((size_t)O * H);       // 1 MB
  unsigned short* hnew_b = carve((size_t)B * H);       // 32 MB
  if (ws_size < need) return;

  auto cast = [&](const float* src, unsigned short* dst, long n) {
    cast_f32_bf16<<<dim3((unsigned)((n / 8 + 255) / 256)), dim3(256), 0, stream>>>(src, dst, n);
  };
  cast(inp,    inp_b,  (long)B * O);
  cast(hidden, h_b,    (long)B * H);
  cast(w_ih,   wih_b,  (long)3 * H * O);
  cast(w_hh,   whh_b,  (long)3 * H * H);
  cast(w_out,  wout_b, (long)O * H);

  // fused GRU cell -> h_new (f32 into d_out tail, bf16 into ws)
  fused_gru<<<dim3(H / 64, B / 128), dim3(256), 0, stream>>>(
      inp_b, h_b, wih_b, whh_b, b_ih, b_hh, hidden, hnew_out, hnew_b);

  // out = tanh(h_new @ w_out^T + b_out)
  gemm_out<<<dim3(O / 128, B / 128), dim3(256), 0, stream>>>(
      hnew_b, wout_b, out, b_out, B, O, H);
}